// Round 16
// baseline (74.217 us; speedup 1.0000x reference)
//
#include <hip/hip_runtime.h>

// ChebFCN2D via MFMA, single fused kernel (pack_w folded in; d_ws unused).
// out[n,o] = b[o] + W[o,0] + sum_{i,j=1..31} W[o,1+(i-1)*31+(j-1)] Ti(x) Tj(y)
// Stage 1 (GEMM, mfma_f32_16x16x32_f16): Z[(o,i'),pt] = sum_k Wpad[(o,i'),k] * T_{k+1}(y_pt)
//   rows R = o*32 + i' (o=0..2, i'=0..31, i'=31 rows zero), K=32 (k=31 zero)
//   6 row-tiles of 16 -> 6 MFMAs per 16-point group.
// Stage 2 (VALU): out[o,pt] = sum_{i'} T_{i'+1}(x_pt) * Z[o*32+i',pt]
//   D-frag: col=lane&15 (point), row=4q+r (q=lane>>4)  [m89-verified; R11-confirmed end-to-end]
// A-frag (R11-confirmed): lane holds A[row=l&15][k=8*(l>>4)+e], e=0..7; built here
//   directly from W (48 scalar loads/lane, L1-resident 11.5 KB) instead of a pack kernel.
// LDS: Ty f16 [64][40], Tx f32 [64][40] (stride 40 breaks power-of-2 bank conflicts).

#define FEAT 962
#define TY_STRIDE 40
#define TX_STRIDE 40

typedef __fp16 half8_t __attribute__((ext_vector_type(8)));
typedef float f32x4 __attribute__((ext_vector_type(4)));

__global__ __launch_bounds__(64) void cheb_mfma_kernel(
    const float* __restrict__ x,     // [N,2]
    const float* __restrict__ W,     // [3,962]
    const float* __restrict__ b,     // [3]
    float* __restrict__ out)         // [N,3]
{
    __shared__ __fp16 TyL[64 * TY_STRIDE];
    __shared__ float  TxL[64 * TX_STRIDE];

    const int l = threadIdx.x;        // 0..63
    const int q = l >> 4;             // 0..3
    const int p16 = l & 15;           // 0..15
    const long nb = (long)blockIdx.x * 64;

    // ---- per-point feature generation (lane l owns point nb+l) ----
    float2 xy = *reinterpret_cast<const float2*>(x + 2 * (nb + l));

    float tx[32], ty[32];
    {
        float c2 = 2.0f * xy.x;
        float tpp = 1.0f, tp = xy.x;
        tx[0] = tp;                         // T_1
#pragma unroll
        for (int m = 1; m < 31; ++m) {      // tx[m] = T_{m+1}
            float tc = c2 * tp - tpp;
            tx[m] = tc;
            tpp = tp; tp = tc;
        }
        tx[31] = 0.0f;                      // pad slot (multiplied by Z=0)
    }
    {
        float c2 = 2.0f * xy.y;
        float tpp = 1.0f, tp = xy.y;
        ty[0] = tp;
#pragma unroll
        for (int m = 1; m < 31; ++m) {
            float tc = c2 * tp - tpp;
            ty[m] = tc;
            tpp = tp; tp = tc;
        }
        ty[31] = 0.0f;                      // pad slot (A k=31 col is zero anyway)
    }

    // Write Tx row (f32, 8x b128)
    {
        float* row = &TxL[l * TX_STRIDE];
#pragma unroll
        for (int c = 0; c < 8; ++c) {
            f32x4 v = { tx[4 * c], tx[4 * c + 1], tx[4 * c + 2], tx[4 * c + 3] };
            *reinterpret_cast<f32x4*>(row + 4 * c) = v;
        }
    }
    // Write Ty row (f16, 4x b128)
    {
        __fp16* row = &TyL[l * TY_STRIDE];
#pragma unroll
        for (int c = 0; c < 4; ++c) {
            half8_t h;
#pragma unroll
            for (int e = 0; e < 8; ++e) h[e] = (__fp16)ty[8 * c + e];
            *reinterpret_cast<half8_t*>(row + 8 * c) = h;
        }
    }

    // ---- A-fragment build directly from W (fused pack; overlaps LDS writes) ----
    // afrag[t][e] = Wpad[16t + p16][8q + e], zero when i'==31 or k==31.
    half8_t afrag[6];
#pragma unroll
    for (int t = 0; t < 6; ++t) {
        int R = 16 * t + p16;
        int o = R >> 5;        // 0..2
        int ip = R & 31;       // i'
        const float* wr = W + o * FEAT + 1 + ip * 31 + 8 * q;
        half8_t h;
#pragma unroll
        for (int e = 0; e < 8; ++e) {
            int k = 8 * q + e;
            float v = (ip < 31 && k < 31) ? wr[e] : 0.0f;
            h[e] = (__fp16)v;
        }
        afrag[t] = h;
    }

    // constant terms
    float c0 = b[0] + W[0 * FEAT];
    float c1 = b[1] + W[1 * FEAT];
    float c2 = b[2] + W[2 * FEAT];

    __syncthreads();

    // ---- 4 groups of 16 points ----
#pragma unroll
    for (int g = 0; g < 4; ++g) {
        int pt = g * 16 + p16;   // this lane's column/point within batch

        // B-fragment: Ty[pt][k = 8q + e]
        half8_t bfrag = *reinterpret_cast<const half8_t*>(&TyL[pt * TY_STRIDE + 8 * q]);
        // Stage-2 Tx values for this lane's D rows: i' = 4q+r and 16+4q+r
        f32x4 txA = *reinterpret_cast<const f32x4*>(&TxL[pt * TX_STRIDE + 4 * q]);
        f32x4 txB = *reinterpret_cast<const f32x4*>(&TxL[pt * TX_STRIDE + 16 + 4 * q]);

        float s0 = 0.f, s1 = 0.f, s2 = 0.f;
#pragma unroll
        for (int t = 0; t < 6; ++t) {
            f32x4 c = { 0.f, 0.f, 0.f, 0.f };
            c = __builtin_amdgcn_mfma_f32_16x16x32_f16(afrag[t], bfrag, c, 0, 0, 0);
            f32x4 ts = (t & 1) ? txB : txA;
            float s = c[0] * ts[0] + c[1] * ts[1] + c[2] * ts[2] + c[3] * ts[3];
            if ((t >> 1) == 0) s0 += s;
            else if ((t >> 1) == 1) s1 += s;
            else s2 += s;
        }
        // reduce over q (lanes differing in bits 4,5)
        s0 += __shfl_xor(s0, 16); s0 += __shfl_xor(s0, 32);
        s1 += __shfl_xor(s1, 16); s1 += __shfl_xor(s1, 32);
        s2 += __shfl_xor(s2, 16); s2 += __shfl_xor(s2, 32);

        // lanes q=0,1,2 store component o=q for point nb+pt
        if (q < 3) {
            float v = (q == 0) ? (s0 + c0) : ((q == 1) ? (s1 + c1) : (s2 + c2));
            out[3 * (nb + pt) + q] = v;
        }
    }
}

extern "C" void kernel_launch(void* const* d_in, const int* in_sizes, int n_in,
                              void* d_out, int out_size, void* d_ws, size_t ws_size,
                              hipStream_t stream) {
    const float* x = (const float*)d_in[0];   // [N,2]
    const float* W = (const float*)d_in[1];   // [3,962]
    const float* b = (const float*)d_in[2];   // [3]
    float* out = (float*)d_out;               // [N,3]

    int N = in_sizes[0] / 2;                  // 262144 = 64 * 4096, no tail

    int grid = N / 64;
    cheb_mfma_kernel<<<grid, 64, 0, stream>>>(x, W, b, out);
}

// Round 17
// 66.026 us; speedup vs baseline: 1.1241x; 1.1241x over previous
//
#include <hip/hip_runtime.h>

// ChebFCN2D via MFMA (R11 two-kernel structure — session best, 65.74 us).
// out[n,o] = b[o] + W[o,0] + sum_{i,j=1..31} W[o,1+(i-1)*31+(j-1)] Ti(x) Tj(y)
// Stage 1 (GEMM, mfma_f32_16x16x32_f16): Z[(o,i'),pt] = sum_k Wpad[(o,i'),k] * T_{k+1}(y_pt)
//   rows R = o*32 + i' (o=0..2, i'=0..31, i'=31 rows zero), K=32 (k=31 zero)
//   6 row-tiles of 16 -> 6 MFMAs per 16-point group.
// Stage 2 (VALU): out[o,pt] = sum_{i'} T_{i'+1}(x_pt) * Z[o*32+i',pt]
//   D-frag: col=lane&15 (point), row=4q+r (q=lane>>4)  [m89-verified; R11-confirmed]
// A-frag (R11-confirmed): lane holds A[row=l&15][k=8*(l>>4)+e], e=0..7.
// Separate pack kernel keeps the main kernel's W loads fully coalesced (R16 showed
// fusing the pack costs +8.5 us from uncoalesced 124B-strided lane addresses).
// LDS: Ty f16 [64][40], Tx f32 [64][40] (stride 40 breaks power-of-2 bank conflicts).

#define FEAT 962
#define TY_STRIDE 40
#define TX_STRIDE 40

typedef __fp16 half8_t __attribute__((ext_vector_type(8)));
typedef float f32x4 __attribute__((ext_vector_type(4)));

// Wpk[t][l][e] = Wpad[16t + (l&15)][8*(l>>4)+e], f16. 6*64*8 = 3072 f16 = 6 KB in d_ws.
__global__ void pack_w_kernel(const float* __restrict__ W, __fp16* __restrict__ Wpk) {
    int idx = blockIdx.x * blockDim.x + threadIdx.x;
    if (idx >= 6 * 64 * 8) return;
    int e = idx & 7;
    int l = (idx >> 3) & 63;
    int t = idx >> 9;
    int R = 16 * t + (l & 15);
    int k = 8 * (l >> 4) + e;
    int o = R >> 5;        // 0..2
    int ip = R & 31;       // i' = 0..31
    float v = (ip < 31 && k < 31) ? W[o * FEAT + 1 + ip * 31 + k] : 0.0f;
    Wpk[idx] = (__fp16)v;
}

__global__ __launch_bounds__(64) void cheb_mfma_kernel(
    const float* __restrict__ x,     // [N,2]
    const float* __restrict__ W,     // [3,962] (for W[o,0])
    const __fp16* __restrict__ Wpk,  // packed A-fragments
    const float* __restrict__ b,     // [3]
    float* __restrict__ out)         // [N,3]
{
    __shared__ __fp16 TyL[64 * TY_STRIDE];
    __shared__ float  TxL[64 * TX_STRIDE];

    const int l = threadIdx.x;        // 0..63
    const int q = l >> 4;             // 0..3
    const int p16 = l & 15;           // 0..15
    const long nb = (long)blockIdx.x * 64;

    // ---- per-point feature generation (lane l owns point nb+l) ----
    float2 xy = *reinterpret_cast<const float2*>(x + 2 * (nb + l));

    float tx[32], ty[32];
    {
        float c2 = 2.0f * xy.x;
        float tpp = 1.0f, tp = xy.x;
        tx[0] = tp;                         // T_1
#pragma unroll
        for (int m = 1; m < 31; ++m) {      // tx[m] = T_{m+1}
            float tc = c2 * tp - tpp;
            tx[m] = tc;
            tpp = tp; tp = tc;
        }
        tx[31] = 0.0f;                      // pad slot (multiplied by Z=0)
    }
    {
        float c2 = 2.0f * xy.y;
        float tpp = 1.0f, tp = xy.y;
        ty[0] = tp;
#pragma unroll
        for (int m = 1; m < 31; ++m) {
            float tc = c2 * tp - tpp;
            ty[m] = tc;
            tpp = tp; tp = tc;
        }
        ty[31] = 0.0f;                      // pad slot (A k=31 col is zero anyway)
    }

    // Write Tx row (f32, 8x b128)
    {
        float* row = &TxL[l * TX_STRIDE];
#pragma unroll
        for (int c = 0; c < 8; ++c) {
            f32x4 v = { tx[4 * c], tx[4 * c + 1], tx[4 * c + 2], tx[4 * c + 3] };
            *reinterpret_cast<f32x4*>(row + 4 * c) = v;
        }
    }
    // Write Ty row (f16, 4x b128)
    {
        __fp16* row = &TyL[l * TY_STRIDE];
#pragma unroll
        for (int c = 0; c < 4; ++c) {
            half8_t h;
#pragma unroll
            for (int e = 0; e < 8; ++e) h[e] = (__fp16)ty[8 * c + e];
            *reinterpret_cast<half8_t*>(row + 8 * c) = h;
        }
    }
    __syncthreads();

    // ---- A-fragment preload (wave-invariant, 6 tiles x 16B per lane, coalesced) ----
    half8_t afrag[6];
#pragma unroll
    for (int t = 0; t < 6; ++t)
        afrag[t] = *reinterpret_cast<const half8_t*>(Wpk + (t * 64 + l) * 8);

    // constant terms
    float c0 = b[0] + W[0 * FEAT];
    float c1 = b[1] + W[1 * FEAT];
    float c2 = b[2] + W[2 * FEAT];

    // ---- 4 groups of 16 points ----
#pragma unroll
    for (int g = 0; g < 4; ++g) {
        int pt = g * 16 + p16;   // this lane's column/point within batch

        // B-fragment: Ty[pt][k = 8q + e]
        half8_t bfrag = *reinterpret_cast<const half8_t*>(&TyL[pt * TY_STRIDE + 8 * q]);
        // Stage-2 Tx values for this lane's D rows: i' = 4q+r and 16+4q+r
        f32x4 txA = *reinterpret_cast<const f32x4*>(&TxL[pt * TX_STRIDE + 4 * q]);
        f32x4 txB = *reinterpret_cast<const f32x4*>(&TxL[pt * TX_STRIDE + 16 + 4 * q]);

        float s0 = 0.f, s1 = 0.f, s2 = 0.f;
#pragma unroll
        for (int t = 0; t < 6; ++t) {
            f32x4 c = { 0.f, 0.f, 0.f, 0.f };
            c = __builtin_amdgcn_mfma_f32_16x16x32_f16(afrag[t], bfrag, c, 0, 0, 0);
            f32x4 ts = (t & 1) ? txB : txA;
            float s = c[0] * ts[0] + c[1] * ts[1] + c[2] * ts[2] + c[3] * ts[3];
            if ((t >> 1) == 0) s0 += s;
            else if ((t >> 1) == 1) s1 += s;
            else s2 += s;
        }
        // reduce over q (lanes differing in bits 4,5)
        s0 += __shfl_xor(s0, 16); s0 += __shfl_xor(s0, 32);
        s1 += __shfl_xor(s1, 16); s1 += __shfl_xor(s1, 32);
        s2 += __shfl_xor(s2, 16); s2 += __shfl_xor(s2, 32);

        // lanes q=0,1,2 store component o=q for point nb+pt
        if (q < 3) {
            float v = (q == 0) ? (s0 + c0) : ((q == 1) ? (s1 + c1) : (s2 + c2));
            out[3 * (nb + pt) + q] = v;
        }
    }
}

extern "C" void kernel_launch(void* const* d_in, const int* in_sizes, int n_in,
                              void* d_out, int out_size, void* d_ws, size_t ws_size,
                              hipStream_t stream) {
    const float* x = (const float*)d_in[0];   // [N,2]
    const float* W = (const float*)d_in[1];   // [3,962]
    const float* b = (const float*)d_in[2];   // [3]
    float* out = (float*)d_out;               // [N,3]
    __fp16* Wpk = (__fp16*)d_ws;              // 6 KB

    int N = in_sizes[0] / 2;                  // 262144 = 64 * 4096, no tail

    pack_w_kernel<<<(6 * 64 * 8 + 255) / 256, 256, 0, stream>>>(W, Wpk);

    int grid = N / 64;
    cheb_mfma_kernel<<<grid, 64, 0, stream>>>(x, W, Wpk, b, out);
}